// Round 4
// baseline (524.883 us; speedup 1.0000x reference)
//
#include <hip/hip_runtime.h>
#include <hip/hip_bf16.h>
#include <math.h>

typedef short short8 __attribute__((ext_vector_type(8)));
typedef float f32x4 __attribute__((ext_vector_type(4)));

__device__ __forceinline__ unsigned short f2bf(float x) {
    unsigned u = __float_as_uint(x);
    u += 0x7FFF + ((u >> 16) & 1);   // RNE
    return (unsigned short)(u >> 16);
}
__device__ __forceinline__ float bf2f(unsigned short h) {
    return __uint_as_float(((unsigned)h) << 16);
}

// Dekker-style split of 2 floats into packed bf16 hi words + bf16 lo words.
__device__ __forceinline__ void cvtpair(float f0, float f1, unsigned& hw, unsigned& lw) {
    __hip_bfloat162 h2 = __float22bfloat162_rn(float2{f0, f1});
    unsigned hu = *(unsigned*)&h2;
    float r0 = f0 - __uint_as_float(hu << 16);
    float r1 = f1 - __uint_as_float(hu & 0xFFFF0000u);
    __hip_bfloat162 l2 = __float22bfloat162_rn(float2{r0, r1});
    hw = hu;
    lw = *(unsigned*)&l2;
}

__device__ __forceinline__ void cvt8(const float4 a, const float4 b, short8& hi, short8& lo) {
    union { unsigned u[4]; short8 s; } H, L;
    cvtpair(a.x, a.y, H.u[0], L.u[0]);
    cvtpair(a.z, a.w, H.u[1], L.u[1]);
    cvtpair(b.x, b.y, H.u[2], L.u[2]);
    cvtpair(b.z, b.w, H.u[3], L.u[3]);
    hi = H.s; lo = L.s;
}

__device__ __forceinline__ float tanh10(float y) {
    float e = __expf(2.f * y);
    return 10.f * (e - 1.f) / (e + 1.f);
}

#define GLDS16(gp, lp)                                                        \
    __builtin_amdgcn_global_load_lds(                                         \
        (const __attribute__((address_space(1))) void*)(gp),                  \
        (__attribute__((address_space(3))) void*)(lp), 16, 0, 0)

// ---------------------------------------------------------------------------
// K0: prep — Wt (fp32 transpose) + bf16 hi/lo split of W (row-major d x k).
// Swizzle pre-applied in global: 16B granule G=k>>3 stored at G^(d&7), so the
// LINEAR global_load_lds staging in k_edge_mfma lands a layout whose
// ds_read_b128 pattern ((kc*4+g)^(col&7)) is 2-way (free) on 32 banks.
// ---------------------------------------------------------------------------
__global__ __launch_bounds__(256) void k_prep(const float* __restrict__ W,
                                              float* __restrict__ Wt,
                                              unsigned short* __restrict__ Whi,
                                              unsigned short* __restrict__ Wlo) {
    int d = blockIdx.x, k = threadIdx.x;
    float w = W[d * 256 + k];
    Wt[k * 256 + d] = w;
    unsigned short hi = f2bf(w);
    int G  = k >> 3;
    int Gp = G ^ (d & 7);
    int idx = d * 256 + Gp * 8 + (k & 7);
    Whi[idx] = hi;
    Wlo[idx] = f2bf(w - bf2f(hi));
}

// ---------------------------------------------------------------------------
// K1: node projection (unchanged)
// ---------------------------------------------------------------------------
__global__ __launch_bounds__(256) void k_node_proj(const float* __restrict__ nodes,
                                                   const float* __restrict__ Wt,
                                                   const float* __restrict__ bias,
                                                   float* __restrict__ np_) {
    int row = blockIdx.x;
    int d = threadIdx.x;
    __shared__ float xl[256];
    xl[d] = nodes[row * 256 + d];
    __syncthreads();
    float a[8] = {0.f, 0.f, 0.f, 0.f, 0.f, 0.f, 0.f, 0.f};
#pragma unroll 4
    for (int k = 0; k < 256; k += 8) {
#pragma unroll
        for (int q = 0; q < 8; ++q)
            a[q] = fmaf(xl[k + q], Wt[(k + q) * 256 + d], a[q]);
    }
    np_[row * 256 + d] =
        bias[d] + ((a[0] + a[1]) + (a[2] + a[3])) + ((a[4] + a[5]) + (a[6] + a[7]));
}

// ---------------------------------------------------------------------------
// K2: MFMA edge scores — whole W panel staged ONCE, ZERO-barrier main loop,
// 2-deep E register pipeline.
//   Block = 256 edges (full j row of one (b,i)) x 64 dims (2 heads).
//   grid = 4096 (1024 tiles x 4 quarters), XCD-grouped: the 4 quarters of a
//   tile run on the same XCD back-to-back -> E row shared via L2.
//   Wave w owns j in [w*64, w*64+64): mt=4 rows x nt=4 cols, acc = 64 regs.
//   Prologue: 16 glds stage the full 64x256 hi/lo W panel (swizzled layout);
//   E(0),E(1) into register dbuf; ONE counted-vmcnt barrier. Main loop has
//   no LDS writes -> no barriers: cvt E(kc) [auto vmcnt(8)], issue E(kc+2),
//   MFMA phase [lgkm only]. Waves free-run and self-stagger.
//   acc = Eh*Wh + Eh*Wl + El*Wh  (fp32 acc; dropped El*Wl ~2^-17 rel).
//   Softmax fused in epilogue.
// ---------------------------------------------------------------------------
__global__ __launch_bounds__(256, 2) void k_edge_mfma(const float* __restrict__ edges,
                                                      const unsigned short* __restrict__ Whi,
                                                      const unsigned short* __restrict__ Wlo,
                                                      const float* __restrict__ bias,
                                                      const float* __restrict__ np_,
                                                      float* __restrict__ attn) {
    __shared__ unsigned short Wf[2][64 * 256];   // [hi/lo][row][granule] 64 KB
    __shared__ float npi[64];
    __shared__ float sc[2][256];

    const int t = threadIdx.x;
    const int w = t >> 6, l = t & 63;
    const int col = l & 15, g = l >> 4;
    const int cx = col & 7;

    // XCD grouping: each XCD gets a contiguous logical range (128 tiles x 4
    // quarters); the 4 quarters of a tile are adjacent in time on one XCD.
    const int p = blockIdx.x;
    const int L = (p & 7) * 512 + (p >> 3);
    const int tile = L >> 2, quarter = L & 3;
    const int bb = tile >> 8, ii = tile & 255;
    const int n0 = quarter * 64;                 // dims n0..n0+63 (2 heads)

    // ---- prologue, vm issue order pinned with sched_barrier:
    // [1] npi load  [2..17] 16 glds (W panel)  [18..33] E(0),E(1)
    float4 npiv = ((const float4*)(np_ + (size_t)(bb * 256 + ii) * 256 + n0))[l & 15];
    __builtin_amdgcn_sched_barrier(0);

#pragma unroll
    for (int m = 0; m < 2; ++m) {
        const unsigned short* gs = (m ? Wlo : Whi) +
            (size_t)(n0 + w * 16 + (l >> 5)) * 256 + (l & 31) * 8;
#pragma unroll
        for (int i = 0; i < 8; ++i)
            GLDS16(gs + (size_t)(2 * i) * 256, &Wf[m][(w * 16 + 2 * i) * 256]);
    }
    __builtin_amdgcn_sched_barrier(0);

    const float* ea = edges + ((size_t)((bb * 256 + ii) * 256 + w * 64 + col)) * 256 + g * 8;
    float4 e0[4][2], e1[4][2];
#pragma unroll
    for (int mt = 0; mt < 4; ++mt) {
        e0[mt][0] = *(const float4*)(ea + mt * 4096);
        e0[mt][1] = *(const float4*)(ea + mt * 4096 + 4);
    }
#pragma unroll
    for (int mt = 0; mt < 4; ++mt) {
        e1[mt][0] = *(const float4*)(ea + 32 + mt * 4096);
        e1[mt][1] = *(const float4*)(ea + 32 + mt * 4096 + 4);
    }
    if (l < 16) ((float4*)npi)[l] = npiv;   // auto-waits vmcnt(32)
    __builtin_amdgcn_sched_barrier(0);
    // retire npi + 16 glds (17 oldest); 16 E loads stay IN FLIGHT
    asm volatile("s_waitcnt vmcnt(16) lgkmcnt(0)\n\ts_barrier" ::: "memory");

    f32x4 acc[4][4];
#pragma unroll
    for (int mt = 0; mt < 4; ++mt)
#pragma unroll
        for (int nt = 0; nt < 4; ++nt) acc[mt][nt] = (f32x4){0.f, 0.f, 0.f, 0.f};

    short8 Ah[4], Al[4];

#pragma unroll
    for (int kc = 0; kc < 8; ++kc) {
        // ---- convert E(kc): compiler emits vmcnt(8) (E(kc+1) stays in flight)
        if (kc & 1) {
#pragma unroll
            for (int mt = 0; mt < 4; ++mt) cvt8(e1[mt][0], e1[mt][1], Ah[mt], Al[mt]);
        } else {
#pragma unroll
            for (int mt = 0; mt < 4; ++mt) cvt8(e0[mt][0], e0[mt][1], Ah[mt], Al[mt]);
        }
        __builtin_amdgcn_sched_barrier(0);
        // ---- issue E(kc+2) into the buffer cvt just freed (2-deep pipeline)
        if (kc < 6) {
            if (kc & 1) {
#pragma unroll
                for (int mt = 0; mt < 4; ++mt) {
                    e1[mt][0] = *(const float4*)(ea + (kc + 2) * 32 + mt * 4096);
                    e1[mt][1] = *(const float4*)(ea + (kc + 2) * 32 + mt * 4096 + 4);
                }
            } else {
#pragma unroll
                for (int mt = 0; mt < 4; ++mt) {
                    e0[mt][0] = *(const float4*)(ea + (kc + 2) * 32 + mt * 4096);
                    e0[mt][1] = *(const float4*)(ea + (kc + 2) * 32 + mt * 4096 + 4);
                }
            }
        }
        __builtin_amdgcn_sched_barrier(0);
        // ---- MFMA phase (lgkm waits only; LDS panel is read-only)
        const int gofs = (((kc << 2) | g) ^ cx) << 3;   // swizzled granule
        const unsigned short* bh = &Wf[0][col * 256 + gofs];
        const unsigned short* bl = &Wf[1][col * 256 + gofs];
        __builtin_amdgcn_s_setprio(1);
#pragma unroll
        for (int nt = 0; nt < 4; ++nt) {
            short8 Bh = *(const short8*)(bh + nt * 4096);
            short8 Bl = *(const short8*)(bl + nt * 4096);
#pragma unroll
            for (int mt = 0; mt < 4; ++mt) {
                acc[mt][nt] = __builtin_amdgcn_mfma_f32_16x16x32_bf16(Ah[mt], Bh, acc[mt][nt], 0, 0, 0);
                acc[mt][nt] = __builtin_amdgcn_mfma_f32_16x16x32_bf16(Ah[mt], Bl, acc[mt][nt], 0, 0, 0);
                acc[mt][nt] = __builtin_amdgcn_mfma_f32_16x16x32_bf16(Al[mt], Bh, acc[mt][nt], 0, 0, 0);
            }
        }
        __builtin_amdgcn_s_setprio(0);
        __builtin_amdgcn_sched_barrier(0);
    }

    // ---- epilogue: scores for the 2 heads of this quarter
    const float isq = 0.17677669529663687f;  // 1/sqrt(32)
    float bv[4], nv[4];
#pragma unroll
    for (int nt = 0; nt < 4; ++nt) {
        int dl = nt * 16 + col;
        bv[nt] = bias[n0 + dl];
        nv[nt] = npi[dl];
    }
#pragma unroll
    for (int mt = 0; mt < 4; ++mt) {
#pragma unroll
        for (int r = 0; r < 4; ++r) {
            int el = w * 64 + mt * 16 + g * 4 + r;   // j index 0..255
            const float* npj = np_ + (size_t)(bb * 256 + el) * 256 + n0;
            float pp, s0 = 0.f, s1 = 0.f;
            pp = acc[mt][0][r] + bv[0]; s0 += (pp + nv[0]) * (pp + npj[col]);
            pp = acc[mt][1][r] + bv[1]; s0 += (pp + nv[1]) * (pp + npj[16 + col]);
            pp = acc[mt][2][r] + bv[2]; s1 += (pp + nv[2]) * (pp + npj[32 + col]);
            pp = acc[mt][3][r] + bv[3]; s1 += (pp + nv[3]) * (pp + npj[48 + col]);
#pragma unroll
            for (int m = 1; m < 16; m <<= 1) {
                s0 += __shfl_xor(s0, m, 64);
                s1 += __shfl_xor(s1, m, 64);
            }
            if (col == 0) {
                sc[0][el] = tanh10(s0 * isq);
                sc[1][el] = tanh10(s1 * isq);
            }
        }
    }
    __syncthreads();

    // ---- fused softmax: waves 0,1 normalize head rows (quarter*2 + w)
    if (w < 2) {
        float4 v = *(float4*)&sc[w][l * 4];
        float m = fmaxf(fmaxf(v.x, v.y), fmaxf(v.z, v.w));
#pragma unroll
        for (int s = 1; s < 64; s <<= 1) m = fmaxf(m, __shfl_xor(m, s, 64));
        v.x = __expf(v.x - m); v.y = __expf(v.y - m);
        v.z = __expf(v.z - m); v.w = __expf(v.w - m);
        float sum = v.x + v.y + v.z + v.w;
#pragma unroll
        for (int s = 1; s < 64; s <<= 1) sum += __shfl_xor(sum, s, 64);
        float inv = 1.f / sum;
        v.x *= inv; v.y *= inv; v.z *= inv; v.w *= inv;
        *(float4*)(attn + (((size_t)(bb * 8 + quarter * 2 + w) * 256 + ii) << 8) + l * 4) = v;
    }
}

// ---------------------------------------------------------------------------
// K4: out = proj(attn @ np) (unchanged)
// ---------------------------------------------------------------------------
__global__ __launch_bounds__(256) void k_out(const float* __restrict__ attn,
                                             const float* __restrict__ np_,
                                             const float* __restrict__ Wt,
                                             const float* __restrict__ bias,
                                             float* __restrict__ out) {
    int bi = blockIdx.x;
    int bb = bi >> 8, ii = bi & 255;
    int d = threadIdx.x;
    __shared__ float at[8 * 256];
    __shared__ float xl[256];
#pragma unroll
    for (int s = 0; s < 2; ++s) {
        int idx = d + s * 256;
        int h = idx >> 6, q = idx & 63;
        ((float4*)at)[idx] =
            ((const float4*)(attn + ((size_t)(bb * 8 + h) * 256 + ii) * 256))[q];
    }
    __syncthreads();
    int h = d >> 5;
    const float* npb = np_ + (size_t)bb * 65536 + d;
    const float* ath = at + h * 256;
    float a[8] = {0.f, 0.f, 0.f, 0.f, 0.f, 0.f, 0.f, 0.f};
#pragma unroll 2
    for (int j = 0; j < 256; j += 8) {
#pragma unroll
        for (int q = 0; q < 8; ++q)
            a[q] = fmaf(ath[j + q], npb[(size_t)(j + q) * 256], a[q]);
    }
    xl[d] = ((a[0] + a[1]) + (a[2] + a[3])) + ((a[4] + a[5]) + (a[6] + a[7]));
    __syncthreads();
    float c[8] = {bias[d], 0.f, 0.f, 0.f, 0.f, 0.f, 0.f, 0.f};
#pragma unroll 2
    for (int k = 0; k < 256; k += 8) {
#pragma unroll
        for (int q = 0; q < 8; ++q)
            c[q] = fmaf(xl[k + q], Wt[(k + q) * 256 + d], c[q]);
    }
    out[bi * 256 + d] =
        ((c[0] + c[1]) + (c[2] + c[3])) + ((c[4] + c[5]) + (c[6] + c[7]));
}

// ---------------------------------------------------------------------------
extern "C" void kernel_launch(void* const* d_in, const int* in_sizes, int n_in,
                              void* d_out, int out_size, void* d_ws, size_t ws_size,
                              hipStream_t stream) {
    (void)in_sizes; (void)n_in; (void)out_size; (void)ws_size;
    const float* nodes = (const float*)d_in[0];
    const float* edges = (const float*)d_in[1];
    const float* W     = (const float*)d_in[2];
    const float* bias  = (const float*)d_in[3];

    float* out  = (float*)d_out;            // (4,256,256)
    float* attn = out + 262144;             // (4,8,256,256)

    float* np_ = (float*)d_ws;              // 262144 floats
    float* Wt  = np_ + 262144;              // 65536 floats
    unsigned short* Whi = (unsigned short*)(Wt + 65536);  // 65536 bf16
    unsigned short* Wlo = Whi + 65536;                    // 65536 bf16

    hipLaunchKernelGGL(k_prep,      dim3(256),  dim3(256), 0, stream, W, Wt, Whi, Wlo);
    hipLaunchKernelGGL(k_node_proj, dim3(1024), dim3(256), 0, stream, nodes, Wt, bias, np_);
    hipLaunchKernelGGL(k_edge_mfma, dim3(4096), dim3(256), 0, stream, edges, Whi, Wlo, bias, np_, attn);
    hipLaunchKernelGGL(k_out,       dim3(1024), dim3(256), 0, stream, attn, np_, Wt, bias, out);
}